// Round 19
// baseline (229.036 us; speedup 1.0000x reference)
//
#include <hip/hip_runtime.h>

// Problem constants
#define B_Q   4096
#define E_DIM 512
#define N_C   2000
#define N_P   64000

// Round 18: BARRIER-FREE, LDS-FREE int8 GEMM.  r12/r13/r15/r17 all plateau
// at 159-162us (MfmaUtil ~38%) across four different schedules -- the
// invariant is the barrier-coupled phase structure (per-SIMD: 163k cyc MFMA
// vs 388k wall; each wave-iter slot ~2300 cyc of which 320 is MFMA; the rest
// is s_barrier/waitcnt convoy across 4 SIMDs x 3 blocks).  Fix: make every
// wave self-sufficient.  BOTH operands are fragment-packed by normq (the
// transform r17 verified end-to-end); a wave owns 64 rows x 512 cols, holds
// ALL 32 A-fragments register-resident (loaded once), streams B per 64-col
// group as 4x1KB coalesced L2 loads per k-tile (dual-set dbuf, compiler
// auto-waitcnt).  Zero s_barrier, zero LDS, zero lgkmcnt in the k-loop.
// L2 budget: B 2.0GB + A 0.26GB = 2.3GB ~ 67us at ceiling ~ MFMA floor 68us.

typedef int i32x4 __attribute__((ext_vector_type(4)));

// ---------------------------------------------------------------------------
// Row L2-normalize + per-row-scaled int8 quantization + FRAGMENT PACKING
// (both inputs).  For row c = c16*16 + r, element k = kt*64 + kg*16 + b:
//   dst[(c16*8 + kt)*1024 + (kg*16 + r)*16 + b]
// A wave's fragment load for (c16, kt) is dst[(c16*8+kt)*1024 + lane*16]
// -- one contiguous 1KB transaction.  (Transform verified on HW in r17.)
// ---------------------------------------------------------------------------
__global__ __launch_bounds__(128) void normq_kernel(
    const float* __restrict__ w1, const float* __restrict__ data,
    signed char* __restrict__ wqf, signed char* __restrict__ dqf,
    float* __restrict__ wsc, float* __restrict__ dsc)
{
  int row = blockIdx.x;
  const bool isW = (row < N_P);
  const float* in;
  signed char* dst; float* sc;
  if (isW) { in = w1;   dst = wqf; sc = wsc; }
  else     { in = data; dst = dqf; sc = dsc; row -= N_P; }
  const int tid = threadIdx.x;
  const float4 v = *(const float4*)(in + (size_t)row * E_DIM + tid * 4);
  float ss = v.x*v.x + v.y*v.y + v.z*v.z + v.w*v.w;
  float am = fmaxf(fmaxf(fabsf(v.x), fabsf(v.y)), fmaxf(fabsf(v.z), fabsf(v.w)));
  #pragma unroll
  for (int s = 1; s < 64; s <<= 1) {
    ss += __shfl_xor(ss, s);
    am = fmaxf(am, __shfl_xor(am, s));
  }
  __shared__ float pss[2], pam[2];
  if ((tid & 63) == 0) { pss[tid >> 6] = ss; pam[tid >> 6] = am; }
  __syncthreads();
  const float inv = 1.0f / fmaxf(sqrtf(pss[0] + pss[1]), 1e-12f);
  const float m   = fmaxf(fmaxf(pam[0], pam[1]) * inv, 1e-20f);
  const float qs  = 127.0f / m * inv;          // v * qs in [-127, 127]
  char4 o;
  o.x = (signed char)__float2int_rn(v.x * qs);
  o.y = (signed char)__float2int_rn(v.y * qs);
  o.z = (signed char)__float2int_rn(v.z * qs);
  o.w = (signed char)__float2int_rn(v.w * qs);
  // k = tid*4: kt = tid>>4, kg = (tid>>2)&3, byte-in-chunk = (tid&3)*4
  const int c16 = row >> 4, r = row & 15;
  const int kt = tid >> 4, kg = (tid >> 2) & 3;
  *(char4*)(dst + (size_t)(c16 * 8 + kt) * 1024 + (kg * 16 + r) * 16
                + (tid & 3) * 4) = o;
  if (tid == 0) sc[row] = m * (1.0f / 127.0f);
}

// ---------------------------------------------------------------------------
// Per-wave GEMM+max: wave w covers rows [rowGroup*64, +64) x cols
// [colOct*512, +512).  A[4 m-tiles][8 kt] register-resident (128 VGPR).
// Sweep 8 col-groups (64 cols = 4 c16-tiles); per kt: 4 B loads (1KB
// coalesced each) + 16 MFMA; B dual-set, kt7 prefetches next col-group's
// kt0 (always issued; harmless over-read inside d_ws for the last group).
// No barriers, no LDS; load->MFMA ordering via compiler auto-waitcnt.
// ---------------------------------------------------------------------------
#define MF(a,b,c) __builtin_amdgcn_mfma_i32_16x16x64_i8(a, b, c, 0, 0, 0)

#define LDB(S,OFF,KT) do { \
  b##S##0 = *(const i32x4*)(gBc + (OFF) + (0*8+(KT))*1024); \
  b##S##1 = *(const i32x4*)(gBc + (OFF) + (1*8+(KT))*1024); \
  b##S##2 = *(const i32x4*)(gBc + (OFF) + (2*8+(KT))*1024); \
  b##S##3 = *(const i32x4*)(gBc + (OFF) + (3*8+(KT))*1024); \
} while(0)

#define MFMA_KT(S,KT) do { \
  acc[0][0]=MF(A[0][KT],b##S##0,acc[0][0]); acc[0][1]=MF(A[0][KT],b##S##1,acc[0][1]); \
  acc[0][2]=MF(A[0][KT],b##S##2,acc[0][2]); acc[0][3]=MF(A[0][KT],b##S##3,acc[0][3]); \
  acc[1][0]=MF(A[1][KT],b##S##0,acc[1][0]); acc[1][1]=MF(A[1][KT],b##S##1,acc[1][1]); \
  acc[1][2]=MF(A[1][KT],b##S##2,acc[1][2]); acc[1][3]=MF(A[1][KT],b##S##3,acc[1][3]); \
  acc[2][0]=MF(A[2][KT],b##S##0,acc[2][0]); acc[2][1]=MF(A[2][KT],b##S##1,acc[2][1]); \
  acc[2][2]=MF(A[2][KT],b##S##2,acc[2][2]); acc[2][3]=MF(A[2][KT],b##S##3,acc[2][3]); \
  acc[3][0]=MF(A[3][KT],b##S##0,acc[3][0]); acc[3][1]=MF(A[3][KT],b##S##1,acc[3][1]); \
  acc[3][2]=MF(A[3][KT],b##S##2,acc[3][2]); acc[3][3]=MF(A[3][KT],b##S##3,acc[3][3]); \
} while(0)

__global__ __launch_bounds__(256, 2) void gemm_max_kernel(
    const signed char* __restrict__ wqf,  // [4000][8][1024] fragment-packed
    const signed char* __restrict__ dqf,  // [256][8][1024]  fragment-packed
    const float* __restrict__ wsc,        // [64000] dequant scales
    const float* __restrict__ dsc,        // [4096]  dequant scales
    float* __restrict__ out)              // [2000][4096]
{
  const int tid  = threadIdx.x;
  const int lane = tid & 63;
  const int wid  = tid >> 6;      // 0..3

  // XCD-aware bijective swizzle: 2000 blocks, 250/XCD.
  const int bid  = blockIdx.x;
  const int wgid = (bid & 7) * 250 + (bid >> 3);
  const int w    = wgid * 4 + wid;        // wave id 0..7999
  const int rowGroup = w >> 3;            // 0..999   (64 rows each)
  const int colOct   = w & 7;             // 0..7     (512 cols each)

  // A: all 32 fragments register-resident.  r16-tile = rowGroup*4 + m.
  const signed char* gAp = wqf + (size_t)rowGroup * 32768 + lane * 16;
  i32x4 A[4][8];
  #pragma unroll
  for (int m = 0; m < 4; ++m)
    #pragma unroll
    for (int kt = 0; kt < 8; ++kt)
      A[m][kt] = *(const i32x4*)(gAp + (m * 8 + kt) * 1024);

  // B base for first col-group; advances by 32768 per group.
  const signed char* gBc = dqf + (size_t)colOct * 8 * 32768 + lane * 16;

  const int r  = lane & 15;
  const int kg = lane >> 4;

  i32x4 b00, b01, b02, b03, b10, b11, b12, b13;
  i32x4 acc[4][4];

  // Prologue: B(kt0) of first col-group into set 0.
  LDB(0, 0, 0);

  float* outp = out + (size_t)(rowGroup * 2) * B_Q + colOct * 512;
  const float* wscp = wsc + rowGroup * 64 + kg * 4;
  const float* dscp = dsc + colOct * 512 + r;

  #pragma unroll 1
  for (int cc = 0; cc < 8; ++cc) {
    #pragma unroll
    for (int m = 0; m < 4; ++m)
      #pragma unroll
      for (int n = 0; n < 4; ++n)
        acc[m][n] = (i32x4){0, 0, 0, 0};

    // kt loop, fully unrolled; set(kt) = kt&1; during kt load set(kt+1).
    LDB(1, 0, 1);       MFMA_KT(0, 0);
    LDB(0, 0, 2);       MFMA_KT(1, 1);
    LDB(1, 0, 3);       MFMA_KT(0, 2);
    LDB(0, 0, 4);       MFMA_KT(1, 3);
    LDB(1, 0, 5);       MFMA_KT(0, 4);
    LDB(0, 0, 6);       MFMA_KT(1, 5);
    LDB(1, 0, 7);       MFMA_KT(0, 6);
    LDB(0, 32768, 0);   MFMA_KT(1, 7);   // prefetch next col-group's kt0

    // Epilogue for this 64-col group: dequant + per-class max.
    // Wave row = m*16 + kg*4 + j; class q = m>>1.  Row scale BEFORE max.
    #pragma unroll
    for (int q = 0; q < 2; ++q) {
      const float4 w0 = *(const float4*)(wscp + (2*q)     * 16);
      const float4 w1 = *(const float4*)(wscp + (2*q + 1) * 16);
      #pragma unroll
      for (int n = 0; n < 4; ++n) {
        float pm = fmaxf(fmaxf((float)acc[2*q][n][0]   * w0.x,
                               (float)acc[2*q][n][1]   * w0.y),
                         fmaxf((float)acc[2*q][n][2]   * w0.z,
                               (float)acc[2*q][n][3]   * w0.w));
        pm = fmaxf(pm, fmaxf(fmaxf((float)acc[2*q+1][n][0] * w1.x,
                                   (float)acc[2*q+1][n][1] * w1.y),
                             fmaxf((float)acc[2*q+1][n][2] * w1.z,
                                   (float)acc[2*q+1][n][3] * w1.w)));
        pm = fmaxf(pm, __shfl_xor(pm, 16));
        pm = fmaxf(pm, __shfl_xor(pm, 32));
        if (lane < 16)
          outp[(size_t)q * B_Q + cc * 64 + n * 16 + r]
              = pm * dscp[cc * 64 + n * 16];
      }
    }
    gBc += 32768;
  }
}

// ---------------------------------------------------------------------------
extern "C" void kernel_launch(void* const* d_in, const int* in_sizes, int n_in,
                              void* d_out, int out_size, void* d_ws, size_t ws_size,
                              hipStream_t stream) {
  const float* data = (const float*)d_in[0];   // [4096][512]
  const float* w1   = (const float*)d_in[1];   // [64000][512]
  float* out = (float*)d_out;                  // [2000][4096]

  signed char* wqf = (signed char*)d_ws;                      // 32.77 MB
  signed char* dqf = wqf + (size_t)N_P * E_DIM;               //  2.10 MB
  float* wsc = (float*)(dqf + (size_t)B_Q * E_DIM);           // 256 KB
  float* dsc = wsc + N_P;                                     //  16 KB

  normq_kernel<<<N_P + B_Q, 128, 0, stream>>>(w1, data, wqf, dqf, wsc, dsc);
  gemm_max_kernel<<<2000, 256, 0, stream>>>(wqf, dqf, wsc, dsc, out);
}